// Round 8
// baseline (429.250 us; speedup 1.0000x reference)
//
#include <hip/hip_runtime.h>

#define NN 50000
#define EE 800000
#define NB 196   // ceil(NN/256)

typedef __bf16 bf16x8 __attribute__((ext_vector_type(8)));
typedef float  f32x4  __attribute__((ext_vector_type(4)));

__device__ __forceinline__ float bf2f(ushort u) {
    union { unsigned int i; float f; } v; v.i = ((unsigned int)u) << 16; return v.f;
}
__device__ __forceinline__ ushort f2bf(float f) {        // RNE
    union { float f; unsigned int i; } v; v.f = f;
    unsigned int u = v.i;
    return (ushort)((u + 0x7FFFu + ((u >> 16) & 1u)) >> 16);
}
__device__ __forceinline__ ushort f2bf_fast(float f) {
    union { float f; unsigned int i; } v; v.f = f;
    return (ushort)((v.i + 0x8000u) >> 16);
}
// fast silu: v_rcp_f32 instead of IEEE division (error ~1ulp f32 << bf16 rounding)
__device__ __forceinline__ float silu(float x) {
    return x * __builtin_amdgcn_rcpf(1.0f + __expf(-x));
}

// Inline dtype detection: every 256-thread block samples the first 256
// bf16-candidates of xz; if they look sane (finite, |v|<=4) input is bf16.
__device__ __forceinline__ bool detect_isf(const ushort* __restrict__ xzu,
                                           int tid, int* scnt) {
    float v = bf2f(xzu[2 * (tid & 255)]);
    bool sane = (v == v) && (fabsf(v) <= 4.0f);
    unsigned long long m = __ballot(sane);
    if ((tid & 63) == 0) scnt[tid >> 6] = __popcll(m);
    __syncthreads();
    int cnt = scnt[0] + scnt[1] + scnt[2] + scnt[3];
    return cnt < 192;   // true -> f32 input
}

// ---------------------------------------------------------------------------
// prep_all: [0,3125) h->bf16; [3125,3712) xz->f32; [3712,6837) degree;
//           [6837,6886) weight swizzle + misc
// ---------------------------------------------------------------------------
__global__ void prep_all_kernel(const void* __restrict__ hsrc, const void* __restrict__ xzsrc,
                                const int* __restrict__ erow,
                                const void* We1, const void* We2,
                                const void* Wn1, const void* Wn2,
                                const void* be1, const void* be2,
                                const void* bn1, const void* bn2,
                                ushort* __restrict__ hb, float* __restrict__ xzf,
                                int* __restrict__ cntI,
                                ushort* __restrict__ We1s, ushort* __restrict__ We2s,
                                ushort* __restrict__ Wn1s, ushort* __restrict__ Wn2s,
                                float* __restrict__ fb, ushort* __restrict__ wlb) {
    __shared__ int scnt[4];
    const int b = blockIdx.x;
    const int tid = threadIdx.x;

    if (b >= 3712 && b < 6837) {          // degree count: no dtype needed
        int e = (b - 3712) * 256 + tid;
        if (e < EE) atomicAdd(&cntI[erow[e]], 1);
        return;
    }

    const bool isf = detect_isf((const ushort*)xzsrc, tid, scnt);

    if (b < 3125) {                        // h -> bf16 (8 elems/thread)
        int i = (b * 256 + tid) * 8;
        uint4 o;
        if (isf) {
            const float* s = (const float*)hsrc + i;
            float4 f0 = *(const float4*)s;
            float4 f1 = *(const float4*)(s + 4);
            o.x = (unsigned int)f2bf(f0.x) | ((unsigned int)f2bf(f0.y) << 16);
            o.y = (unsigned int)f2bf(f0.z) | ((unsigned int)f2bf(f0.w) << 16);
            o.z = (unsigned int)f2bf(f1.x) | ((unsigned int)f2bf(f1.y) << 16);
            o.w = (unsigned int)f2bf(f1.z) | ((unsigned int)f2bf(f1.w) << 16);
        } else {
            o = *(const uint4*)((const ushort*)hsrc + i);
        }
        *(uint4*)(hb + i) = o;
    } else if (b < 3712) {                 // xz -> f32
        int i = (b - 3125) * 256 + tid;
        if (i < NN * 3)
            xzf[i] = isf ? ((const float*)xzsrc)[i] : bf2f(((const ushort*)xzsrc)[i]);
    } else {                               // weight swizzle / misc
        int sw = b - 6837;
        if (sw == 48) {
            for (int j = tid; j < 640; j += 256) {
                int which = j >> 7, k = j & 127;
                const void* src = (which == 0) ? be1 : (which == 1) ? be2 :
                                  (which == 2) ? bn1 : (which == 3) ? bn2 : We1;
                size_t idx = (which == 4) ? ((size_t)256 * 128 + k) : (size_t)k;
                float v = isf ? ((const float*)src)[idx] : bf2f(((const ushort*)src)[idx]);
                fb[j] = v;
                if (which == 4) wlb[k] = f2bf(v);
            }
            return;
        }
        int c = sw * 256 + tid;
        const void* src; ushort* dst; int cl;
        if      (c <  4096) { src = We1; dst = We1s; cl = c;         }
        else if (c <  6144) { src = We2; dst = We2s; cl = c - 4096;  }
        else if (c < 10240) { src = Wn1; dst = Wn1s; cl = c - 6144;  }
        else                { src = Wn2; dst = Wn2s; cl = c - 10240; }
        int l = cl & 63, nt = (cl >> 6) & 7, kc = cl >> 9;
        int kbase = kc * 32 + (l >> 4) * 8;
        int n = nt * 16 + (l & 15);
        ushort tmp[8];
#pragma unroll
        for (int j = 0; j < 8; ++j) {
            size_t idx = (size_t)(kbase + j) * 128 + n;
            tmp[j] = isf ? f2bf(((const float*)src)[idx]) : ((const ushort*)src)[idx];
        }
#pragma unroll
        for (int j = 0; j < 8; ++j) dst[(size_t)cl * 8 + j] = tmp[j];
    }
}

// ---------------------------------------------------------------------------
// Counting-sort scan: A) per-block sums  C) scan bsum in-block + write rowStart
// ---------------------------------------------------------------------------
__global__ void scanA_kernel(const int* __restrict__ cntI, int* __restrict__ bsum) {
    __shared__ int s[256];
    int t = threadIdx.x;
    int i = blockIdx.x * 256 + t;
    s[t] = (i < NN) ? cntI[i] : 0;
    __syncthreads();
#pragma unroll
    for (int off = 128; off > 0; off >>= 1) {
        if (t < off) s[t] += s[t + off];
        __syncthreads();
    }
    if (t == 0) bsum[blockIdx.x] = s[0];
}

__global__ void scanC_kernel(const int* __restrict__ cntI, const int* __restrict__ bsum,
                             int* __restrict__ rowStart) {
    __shared__ int s[256];
    __shared__ int sbase;
    int t = threadIdx.x;
    int bv = (t < NB) ? bsum[t] : 0;
    s[t] = bv;
    __syncthreads();
    for (int off = 1; off < 256; off <<= 1) {
        int u = (t >= off) ? s[t - off] : 0;
        __syncthreads();
        if (t >= off) s[t] += u;
        __syncthreads();
    }
    if (t == 0) sbase = (blockIdx.x == 0) ? 0 : s[blockIdx.x - 1];
    __syncthreads();
    int i = blockIdx.x * 256 + t;
    int v = (i < NN) ? cntI[i] : 0;
    s[t] = v;
    __syncthreads();
    for (int off = 1; off < 256; off <<= 1) {
        int u = (t >= off) ? s[t - off] : 0;
        __syncthreads();
        if (t >= off) s[t] += u;
        __syncthreads();
    }
    if (i < NN) rowStart[i] = sbase + s[t] - v;  // global exclusive
}

// ---------------------------------------------------------------------------
// scatter_pq: [0,782) pq GEMM tiles; [782,3907) edge scatter+dist;
//             [3907,4707) zero agg (replaces serialized memset)
// eS entry packed to int2: x = (row<<16)|col (both < 2^16), y = dist bits
// ---------------------------------------------------------------------------
__global__ __launch_bounds__(256, 3) void scatter_pq_kernel(
    const ushort* __restrict__ hb, const ushort* __restrict__ We1s,
    const float* __restrict__ fb, ushort* __restrict__ Pp, ushort* __restrict__ Qq,
    const int* __restrict__ erow, const int* __restrict__ ecol,
    const float* __restrict__ xzf, const int* __restrict__ rowStart,
    int* __restrict__ cursor, int2* __restrict__ eS, uint4* __restrict__ aggz) {
    __shared__ __align__(16) ushort sA[8192];   // used by pq part only
    const int tid = threadIdx.x;

    if (blockIdx.x >= 3907) {
        // ---- zero agg: 1.6e6 uint4s, grid-stride over 800 blocks
        const uint4 z = make_uint4(0, 0, 0, 0);
        int g0 = (blockIdx.x - 3907) * 256 + tid;
        const int total = NN * 128 * 4 / 16;    // 1,600,000
        for (int i = g0; i < total; i += 800 * 256) aggz[i] = z;
        return;
    }
    if (blockIdx.x >= 782) {
        int e = (blockIdx.x - 782) * 256 + tid;
        if (e >= EE) return;
        int r = erow[e], c = ecol[e];
        int pos = rowStart[r] + atomicAdd(&cursor[r], 1);
        float4 a = *(const float4*)(xzf + 3 * r);   // xzf padded by 4 floats
        float4 b = *(const float4*)(xzf + 3 * c);
        float dx = a.x - b.x, dy = a.y - b.y, dz = a.z - b.z;
        float u = (dx * dx + dy * dy + dz * dz) * __builtin_amdgcn_rcpf(2.0f * a.z * b.z);
        u = fminf(fmaxf(u, 0.0f), 1.0e6f);
        float d = __logf(1.0f + u + sqrtf(u * (u + 2.0f)));
        eS[pos] = make_int2((r << 16) | c, __float_as_int(d));
        return;
    }

    const int lane = tid & 63, w = tid >> 6;
    const int col = lane & 15, quad = lane >> 4;
    const int nt0 = w * 2;
    const int nA = w * 32 + col, nB = nA + 16;
    const float be1A = fb[nA], be1B = fb[nB];
    const int tile = blockIdx.x;
    const int n0 = tile * 64;
#pragma unroll
    for (int i = 0; i < 4; ++i) {
        int node = n0 + lane;
        uint4 v = (node < NN) ? *(const uint4*)(hb + (size_t)node * 128 + (w + 4 * i) * 8)
                              : make_uint4(0, 0, 0, 0);
        *(uint4*)(sA + (((lane >> 4) * 4 + i) * 64 + w * 16 + (lane & 15)) * 8) = v;
    }
    __syncthreads();

    f32x4 accP[4][2] = {}, accQ[4][2] = {};
#pragma unroll
    for (int kc = 0; kc < 4; ++kc) {
        bf16x8 bp0 = *(const bf16x8*)(We1s + ((kc * 8 + nt0)           * 64 + lane) * 8);
        bf16x8 bp1 = *(const bf16x8*)(We1s + ((kc * 8 + nt0 + 1)       * 64 + lane) * 8);
        bf16x8 bq0 = *(const bf16x8*)(We1s + (((kc + 4) * 8 + nt0)     * 64 + lane) * 8);
        bf16x8 bq1 = *(const bf16x8*)(We1s + (((kc + 4) * 8 + nt0 + 1) * 64 + lane) * 8);
#pragma unroll
        for (int g = 0; g < 4; ++g) {
            bf16x8 a = *(const bf16x8*)(sA + ((g * 4 + kc) * 64 + lane) * 8);
            accP[g][0] = __builtin_amdgcn_mfma_f32_16x16x32_bf16(a, bp0, accP[g][0], 0, 0, 0);
            accP[g][1] = __builtin_amdgcn_mfma_f32_16x16x32_bf16(a, bp1, accP[g][1], 0, 0, 0);
            accQ[g][0] = __builtin_amdgcn_mfma_f32_16x16x32_bf16(a, bq0, accQ[g][0], 0, 0, 0);
            accQ[g][1] = __builtin_amdgcn_mfma_f32_16x16x32_bf16(a, bq1, accQ[g][1], 0, 0, 0);
        }
    }
#pragma unroll
    for (int g = 0; g < 4; ++g) {
#pragma unroll
        for (int r = 0; r < 4; ++r) {
            int node = n0 + g * 16 + quad * 4 + r;
            if (node < NN) {
                size_t o = (size_t)node * 128;
                Pp[o + nA] = f2bf(accP[g][0][r] + be1A);
                Pp[o + nB] = f2bf(accP[g][1][r] + be1B);
                Qq[o + nA] = f2bf(accQ[g][0][r]);
                Qq[o + nB] = f2bf(accQ[g][1][r]);
            }
        }
    }
}

// ---------------------------------------------------------------------------
// Edge kernel (row-sorted edges), occupancy-focused variant of the proven R5
// structure: sOut shrunk to 32 rows (f32 precision kept) and ep2+reduce done
// in two passes -> LDS 17KB -> 6-8 blocks/CU (was 4). B2 fragments reloaded
// from L2 each tile instead of held resident (-32 VGPRs).
//   per tile: S1 | m1->sM | S2 | GEMM2 | S3 | epA | S4 | redA | S5 | epB | S6 | redB
// ---------------------------------------------------------------------------
__global__ __launch_bounds__(256, 6) void edge_kernel(
    const ushort* __restrict__ Pp, const ushort* __restrict__ Qq,
    const int2* __restrict__ eS, const ushort* __restrict__ We2s,
    const ushort* __restrict__ wlb, const float* __restrict__ fb,
    float* __restrict__ agg) {
    __shared__ __align__(16) char smem[32 * 132 * 4];   // 16896B: sM(16384) | sOut32
    __shared__ int sRow[64];
    ushort* sM = (ushort*)smem;                         // first 16KB
    float (*sOut)[132] = (float(*)[132])smem;           // 32 rows x 132 f32

    const int tid = threadIdx.x;
    const int lane = tid & 63, w = tid >> 6;
    const int col = lane & 15, quad = lane >> 4;
    const int nt0 = w * 2;

    const int nA = w * 32 + col, nB = nA + 16;
    const float be2A = fb[128 + nA], be2B = fb[128 + nB];

    // contiguous tile chunking: consecutive tiles share sorted rows -> locality
    const int ntiles = EE / 64;
    const int per = (ntiles + gridDim.x - 1) / gridDim.x;
    const int t0 = blockIdx.x * per;
    const int t1 = (t0 + per < ntiles) ? (t0 + per) : ntiles;
    if (t0 >= t1) return;

    bf16x8 WL[4];
#pragma unroll
    for (int i = 0; i < 4; ++i) WL[i] = *(const bf16x8*)(wlb + (w + 4 * i) * 8);

    int2 ed = eS[(size_t)t0 * 64 + lane];

    for (int tile = t0; tile < t1; ++tile) {
        const int tn = (tile + 1 < t1) ? (tile + 1) : tile;
        const int2 edn = eS[(size_t)tn * 64 + lane];   // next descriptor only

        __syncthreads();   // S1: prev tile's redB readers done (sOut/sRow free)
        const int r = ((unsigned)ed.x) >> 16, c = ed.x & 0xFFFF;
        const float d = __int_as_float(ed.y);
        if (w == 0) sRow[lane] = r;
        // m1 chunks ch = w+4i for edge m=lane; loads consumed in-phase
#pragma unroll
        for (int i = 0; i < 4; ++i) {
            int ch = w + 4 * i;
            bf16x8 p = *(const bf16x8*)(Pp + (size_t)r * 128 + ch * 8);
            bf16x8 q = *(const bf16x8*)(Qq + (size_t)c * 128 + ch * 8);
            ushort out8[8];
#pragma unroll
            for (int j = 0; j < 8; ++j) {
                float x = (float)p[j] + (float)q[j] + d * (float)WL[i][j];
                out8[j] = f2bf_fast(silu(x));
            }
            *(uint4*)(sM + (((lane >> 4) * 4 + i) * 64 + w * 16 + (lane & 15)) * 8) =
                *(const uint4*)out8;
        }
        ed = edn;
        __syncthreads();   // S2: sM ready

        // ---- GEMM2: m1[64,128] @ We2; B reloaded each tile (L2-hot) ----
        f32x4 acc2[4][2] = {};
        {
            bf16x8 b[8];
#pragma unroll
            for (int kc = 0; kc < 4; ++kc) {
                b[kc * 2]     = *(const bf16x8*)(We2s + ((kc * 8 + nt0)     * 64 + lane) * 8);
                b[kc * 2 + 1] = *(const bf16x8*)(We2s + ((kc * 8 + nt0 + 1) * 64 + lane) * 8);
            }
#pragma unroll
            for (int kc = 0; kc < 4; ++kc) {
#pragma unroll
                for (int g = 0; g < 4; ++g) {
                    bf16x8 a = *(const bf16x8*)(sM + ((g * 4 + kc) * 64 + lane) * 8);
                    acc2[g][0] = __builtin_amdgcn_mfma_f32_16x16x32_bf16(a, b[kc * 2],     acc2[g][0], 0, 0, 0);
                    acc2[g][1] = __builtin_amdgcn_mfma_f32_16x16x32_bf16(a, b[kc * 2 + 1], acc2[g][1], 0, 0, 0);
                }
            }
        }
        __syncthreads();   // S3: all sM reads done -> safe to overwrite as sOut

        // ---- two passes: ep2 (32 rows) + segment reduce (16 rows/thread) ----
#pragma unroll
        for (int pass = 0; pass < 2; ++pass) {
#pragma unroll
            for (int gg = 0; gg < 2; ++gg) {
                int g = pass * 2 + gg;
#pragma unroll
                for (int r4 = 0; r4 < 4; ++r4) {
                    int lr = gg * 16 + quad * 4 + r4;   // local row 0..31
                    sOut[lr][nA] = silu(acc2[g][0][r4] + be2A);
                    sOut[lr][nB] = silu(acc2[g][1][r4] + be2B);
                }
            }
            __syncthreads();   // S4/S6: sOut pass ready

            {
                const int cc = tid & 127;
                const int sub = tid >> 7;                 // 0,1
                const int mb = pass * 32 + sub * 16;      // global row base
                float acc = 0.0f;
                int prow = sRow[mb];
                for (int k = 0; k < 16; ++k) {
                    int rw = sRow[mb + k];
                    if (rw != prow) {
                        unsafeAtomicAdd(&agg[(size_t)prow * 128 + cc], acc);
                        acc = 0.0f;
                        prow = rw;
                    }
                    acc += sOut[sub * 16 + k][cc];
                }
                unsafeAtomicAdd(&agg[(size_t)prow * 128 + cc], acc);
            }
            if (pass == 0) __syncthreads();   // S5: redA done before epB overwrites
        }
    }
}

// ---------------------------------------------------------------------------
// Node kernel: z = [h | agg/max(cnt,1)]; out = h + silu(z@Wn1+bn1)@Wn2+bn2
// ---------------------------------------------------------------------------
__global__ __launch_bounds__(256, 3) void node_kernel(
    const ushort* __restrict__ hb, const void* __restrict__ hraw,
    const void* __restrict__ xzsrc,
    const float* __restrict__ agg, const int* __restrict__ cntI,
    const ushort* __restrict__ Wn1s, const ushort* __restrict__ Wn2s,
    const float* __restrict__ fb, void* __restrict__ outv) {
    __shared__ __align__(16) ushort sA[16384];
    __shared__ __align__(16) ushort sM[8192];
    __shared__ int scnt[4];
    const int tid = threadIdx.x;
    const int lane = tid & 63, w = tid >> 6;
    const int col = lane & 15, quad = lane >> 4;
    const int nt0 = w * 2;
    const int ntiles = (NN + 63) / 64;
    const bool isf = detect_isf((const ushort*)xzsrc, tid, scnt);
    float* outf = (float*)outv;
    ushort* outu = (ushort*)outv;

    const int nA = w * 32 + col, nB = nA + 16;
    const float bn1A = fb[256 + nA], bn1B = fb[256 + nB];
    const float bn2A = fb[384 + nA], bn2B = fb[384 + nB];

    for (int tile = blockIdx.x; tile < ntiles; tile += gridDim.x) {
        __syncthreads();
        const int n0 = tile * 64;
#pragma unroll
        for (int i = 0; i < 8; ++i) {
            int kb = w + 4 * i;
            int node = n0 + lane;
            uint4 v;
            if (node < NN) {
                if (kb < 16) {
                    v = *(const uint4*)(hb + (size_t)node * 128 + kb * 8);
                } else {
                    const float* ap = agg + (size_t)node * 128 + (kb - 16) * 8;
                    float invc = __builtin_amdgcn_rcpf(fmaxf((float)cntI[node], 1.0f));
                    float4 f0 = *(const float4*)ap;
                    float4 f1 = *(const float4*)(ap + 4);
                    v.x = (unsigned int)f2bf_fast(f0.x * invc) | ((unsigned int)f2bf_fast(f0.y * invc) << 16);
                    v.y = (unsigned int)f2bf_fast(f0.z * invc) | ((unsigned int)f2bf_fast(f0.w * invc) << 16);
                    v.z = (unsigned int)f2bf_fast(f1.x * invc) | ((unsigned int)f2bf_fast(f1.y * invc) << 16);
                    v.w = (unsigned int)f2bf_fast(f1.z * invc) | ((unsigned int)f2bf_fast(f1.w * invc) << 16);
                }
            } else {
                v = make_uint4(0, 0, 0, 0);
            }
            *(uint4*)(sA + (((quad * 8 + i) * 64) + w * 16 + col) * 8) = v;
        }
        __syncthreads();

        f32x4 acc[4][2] = {};
#pragma unroll
        for (int kc = 0; kc < 8; ++kc) {
            bf16x8 b0 = *(const bf16x8*)(Wn1s + ((kc * 8 + nt0)     * 64 + lane) * 8);
            bf16x8 b1 = *(const bf16x8*)(Wn1s + ((kc * 8 + nt0 + 1) * 64 + lane) * 8);
#pragma unroll
            for (int g = 0; g < 4; ++g) {
                bf16x8 a = *(const bf16x8*)(sA + ((g * 8 + kc) * 64 + lane) * 8);
                acc[g][0] = __builtin_amdgcn_mfma_f32_16x16x32_bf16(a, b0, acc[g][0], 0, 0, 0);
                acc[g][1] = __builtin_amdgcn_mfma_f32_16x16x32_bf16(a, b1, acc[g][1], 0, 0, 0);
            }
        }
#pragma unroll
        for (int g = 0; g < 4; ++g) {
            int base0 = ((g * 4 + w) * 64 + (col >> 3) * 16) * 8 + (col & 7);
#pragma unroll
            for (int r = 0; r < 4; ++r) {
                int mrow = quad * 4 + r;
                sM[base0 + mrow * 8]              = f2bf_fast(silu(acc[g][0][r] + bn1A));
                sM[base0 + 2 * 16 * 8 + mrow * 8] = f2bf_fast(silu(acc[g][1][r] + bn1B));
            }
        }
        __syncthreads();

        f32x4 acc2[4][2] = {};
#pragma unroll
        for (int kc = 0; kc < 4; ++kc) {
            bf16x8 b0 = *(const bf16x8*)(Wn2s + ((kc * 8 + nt0)     * 64 + lane) * 8);
            bf16x8 b1 = *(const bf16x8*)(Wn2s + ((kc * 8 + nt0 + 1) * 64 + lane) * 8);
#pragma unroll
            for (int g = 0; g < 4; ++g) {
                bf16x8 a = *(const bf16x8*)(sM + ((g * 4 + kc) * 64 + lane) * 8);
                acc2[g][0] = __builtin_amdgcn_mfma_f32_16x16x32_bf16(a, b0, acc2[g][0], 0, 0, 0);
                acc2[g][1] = __builtin_amdgcn_mfma_f32_16x16x32_bf16(a, b1, acc2[g][1], 0, 0, 0);
            }
        }
#pragma unroll
        for (int g = 0; g < 4; ++g) {
#pragma unroll
            for (int r = 0; r < 4; ++r) {
                int ml2 = g * 16 + quad * 4 + r;
                int node = n0 + ml2;
                if (node < NN) {
                    size_t oi = (size_t)node * 128;
                    float h0 = isf ? ((const float*)hraw)[oi + nA] : bf2f(((const ushort*)hraw)[oi + nA]);
                    float h1 = isf ? ((const float*)hraw)[oi + nB] : bf2f(((const ushort*)hraw)[oi + nB]);
                    float x0 = acc2[g][0][r] + bn2A + h0;
                    float x1 = acc2[g][1][r] + bn2B + h1;
                    if (isf) { outf[oi + nA] = x0; outf[oi + nB] = x1; }
                    else     { outu[oi + nA] = f2bf_fast(x0); outu[oi + nB] = f2bf_fast(x1); }
                }
            }
        }
    }
}

extern "C" void kernel_launch(void* const* d_in, const int* in_sizes, int n_in,
                              void* d_out, int out_size, void* d_ws, size_t ws_size,
                              hipStream_t stream) {
    const void* xz  = d_in[0];
    const void* h   = d_in[1];
    const void* We1 = d_in[2];
    const void* be1 = d_in[3];
    const void* We2 = d_in[4];
    const void* be2 = d_in[5];
    const void* Wn1 = d_in[6];
    const void* bn1 = d_in[7];
    const void* Wn2 = d_in[8];
    const void* bn2 = d_in[9];
    const int*  ei  = (const int*)d_in[10];
    const int* erow = ei;
    const int* ecol = ei + EE;

    char* base = (char*)d_ws;
    size_t cur = 0;
    auto alloc = [&](size_t bytes) { size_t o = cur; cur = (cur + bytes + 255) & ~(size_t)255; return o; };
    float*  agg    = (float*) (base + alloc((size_t)NN * 128 * 4));
    int*    cntI   = (int*)   (base + alloc((size_t)NN * 4));
    int*    cursor = (int*)   (base + alloc((size_t)NN * 4));
    ushort* hb     = (ushort*)(base + alloc((size_t)NN * 128 * 2));
    ushort* Pp     = (ushort*)(base + alloc((size_t)NN * 128 * 2));
    ushort* Qq     = (ushort*)(base + alloc((size_t)NN * 128 * 2));
    int2*   eS     = (int2*)  (base + alloc((size_t)EE * 8));
    float*  xzf    = (float*) (base + alloc((size_t)NN * 3 * 4 + 16));   // +pad for float4 loads
    int*    rowSt  = (int*)   (base + alloc((size_t)NN * 4));
    int*    bsum   = (int*)   (base + alloc(256 * 4));
    ushort* We1s   = (ushort*)(base + alloc(32768 * 2));
    ushort* We2s   = (ushort*)(base + alloc(16384 * 2));
    ushort* Wn1s   = (ushort*)(base + alloc(32768 * 2));
    ushort* Wn2s   = (ushort*)(base + alloc(16384 * 2));
    float*  fb     = (float*) (base + alloc(640 * 4));
    ushort* wlb    = (ushort*)(base + alloc(128 * 2));

    // zero ONLY cntI + cursor (adjacent) before prep's atomics; agg is zeroed
    // inside scatter_pq (overlapped), consumed first by edge_kernel afterwards.
    size_t zbytes = (size_t)((char*)hb - (char*)cntI);
    (void)hipMemsetAsync(cntI, 0, zbytes, stream);

    prep_all_kernel<<<6886, 256, 0, stream>>>(h, xz, erow, We1, We2, Wn1, Wn2,
                                              be1, be2, bn1, bn2,
                                              hb, xzf, cntI, We1s, We2s, Wn1s, Wn2s,
                                              fb, wlb);
    scanA_kernel<<<NB, 256, 0, stream>>>(cntI, bsum);
    scanC_kernel<<<NB, 256, 0, stream>>>(cntI, bsum, rowSt);
    scatter_pq_kernel<<<782 + 3125 + 800, 256, 0, stream>>>(hb, We1s, fb, Pp, Qq,
                                                            erow, ecol, xzf, rowSt, cursor,
                                                            eS, (uint4*)agg);
    edge_kernel<<<2048, 256, 0, stream>>>(Pp, Qq, eS, We2s, wlb, fb, agg);
    node_kernel<<<782, 256, 0, stream>>>(hb, h, xz, agg, cntI, Wn1s, Wn2s, fb, d_out);
}

// Round 9
// 347.072 us; speedup vs baseline: 1.2368x; 1.2368x over previous
//
#include <hip/hip_runtime.h>

#define NN 50000
#define EE 800000
#define NB 196   // ceil(NN/256)

typedef __bf16 bf16x8 __attribute__((ext_vector_type(8)));
typedef float  f32x4  __attribute__((ext_vector_type(4)));

__device__ __forceinline__ float bf2f(ushort u) {
    union { unsigned int i; float f; } v; v.i = ((unsigned int)u) << 16; return v.f;
}
__device__ __forceinline__ ushort f2bf(float f) {        // RNE
    union { float f; unsigned int i; } v; v.f = f;
    unsigned int u = v.i;
    return (ushort)((u + 0x7FFFu + ((u >> 16) & 1u)) >> 16);
}
__device__ __forceinline__ ushort f2bf_fast(float f) {
    union { float f; unsigned int i; } v; v.f = f;
    return (ushort)((v.i + 0x8000u) >> 16);
}
// fast silu: v_rcp_f32 instead of IEEE division (error ~1ulp f32 << bf16 rounding)
__device__ __forceinline__ float silu(float x) {
    return x * __builtin_amdgcn_rcpf(1.0f + __expf(-x));
}

// Inline dtype detection: every 256-thread block samples the first 256
// bf16-candidates of xz; if they look sane (finite, |v|<=4) input is bf16.
__device__ __forceinline__ bool detect_isf(const ushort* __restrict__ xzu,
                                           int tid, int* scnt) {
    float v = bf2f(xzu[2 * (tid & 255)]);
    bool sane = (v == v) && (fabsf(v) <= 4.0f);
    unsigned long long m = __ballot(sane);
    if ((tid & 63) == 0) scnt[tid >> 6] = __popcll(m);
    __syncthreads();
    int cnt = scnt[0] + scnt[1] + scnt[2] + scnt[3];
    return cnt < 192;   // true -> f32 input
}

// ---------------------------------------------------------------------------
// prep_all: [0,3125) h->bf16; [3125,3712) xz->f32; [3712,6837) degree;
//           [6837,6886) weight swizzle + misc
// ---------------------------------------------------------------------------
__global__ void prep_all_kernel(const void* __restrict__ hsrc, const void* __restrict__ xzsrc,
                                const int* __restrict__ erow,
                                const void* We1, const void* We2,
                                const void* Wn1, const void* Wn2,
                                const void* be1, const void* be2,
                                const void* bn1, const void* bn2,
                                ushort* __restrict__ hb, float* __restrict__ xzf,
                                int* __restrict__ cntI,
                                ushort* __restrict__ We1s, ushort* __restrict__ We2s,
                                ushort* __restrict__ Wn1s, ushort* __restrict__ Wn2s,
                                float* __restrict__ fb, ushort* __restrict__ wlb) {
    __shared__ int scnt[4];
    const int b = blockIdx.x;
    const int tid = threadIdx.x;

    if (b >= 3712 && b < 6837) {          // degree count: no dtype needed
        int e = (b - 3712) * 256 + tid;
        if (e < EE) atomicAdd(&cntI[erow[e]], 1);
        return;
    }

    const bool isf = detect_isf((const ushort*)xzsrc, tid, scnt);

    if (b < 3125) {                        // h -> bf16 (8 elems/thread)
        int i = (b * 256 + tid) * 8;
        uint4 o;
        if (isf) {
            const float* s = (const float*)hsrc + i;
            float4 f0 = *(const float4*)s;
            float4 f1 = *(const float4*)(s + 4);
            o.x = (unsigned int)f2bf(f0.x) | ((unsigned int)f2bf(f0.y) << 16);
            o.y = (unsigned int)f2bf(f0.z) | ((unsigned int)f2bf(f0.w) << 16);
            o.z = (unsigned int)f2bf(f1.x) | ((unsigned int)f2bf(f1.y) << 16);
            o.w = (unsigned int)f2bf(f1.z) | ((unsigned int)f2bf(f1.w) << 16);
        } else {
            o = *(const uint4*)((const ushort*)hsrc + i);
        }
        *(uint4*)(hb + i) = o;
    } else if (b < 3712) {                 // xz -> f32
        int i = (b - 3125) * 256 + tid;
        if (i < NN * 3)
            xzf[i] = isf ? ((const float*)xzsrc)[i] : bf2f(((const ushort*)xzsrc)[i]);
    } else {                               // weight swizzle / misc
        int sw = b - 6837;
        if (sw == 48) {
            for (int j = tid; j < 640; j += 256) {
                int which = j >> 7, k = j & 127;
                const void* src = (which == 0) ? be1 : (which == 1) ? be2 :
                                  (which == 2) ? bn1 : (which == 3) ? bn2 : We1;
                size_t idx = (which == 4) ? ((size_t)256 * 128 + k) : (size_t)k;
                float v = isf ? ((const float*)src)[idx] : bf2f(((const ushort*)src)[idx]);
                fb[j] = v;
                if (which == 4) wlb[k] = f2bf(v);
            }
            return;
        }
        int c = sw * 256 + tid;
        const void* src; ushort* dst; int cl;
        if      (c <  4096) { src = We1; dst = We1s; cl = c;         }
        else if (c <  6144) { src = We2; dst = We2s; cl = c - 4096;  }
        else if (c < 10240) { src = Wn1; dst = Wn1s; cl = c - 6144;  }
        else                { src = Wn2; dst = Wn2s; cl = c - 10240; }
        int l = cl & 63, nt = (cl >> 6) & 7, kc = cl >> 9;
        int kbase = kc * 32 + (l >> 4) * 8;
        int n = nt * 16 + (l & 15);
        ushort tmp[8];
#pragma unroll
        for (int j = 0; j < 8; ++j) {
            size_t idx = (size_t)(kbase + j) * 128 + n;
            tmp[j] = isf ? f2bf(((const float*)src)[idx]) : ((const ushort*)src)[idx];
        }
#pragma unroll
        for (int j = 0; j < 8; ++j) dst[(size_t)cl * 8 + j] = tmp[j];
    }
}

// ---------------------------------------------------------------------------
// Fused counting-sort scan (196 blocks, all co-resident on 256 CUs):
// phase A: per-block sums -> bsum, arrive at device-scope counter;
// spin until all 196 arrived; phase C: scan bsum + local scan -> rowStart
// ---------------------------------------------------------------------------
__global__ void scan_fused_kernel(const int* __restrict__ cntI, int* __restrict__ bsum,
                                  int* __restrict__ rowStart, int* __restrict__ done) {
    __shared__ int s[256];
    __shared__ int sbase;
    const int t = threadIdx.x;
    const int b = blockIdx.x;
    const int i = b * 256 + t;
    const int v = (i < NN) ? cntI[i] : 0;

    // phase A: block total
    s[t] = v;
    __syncthreads();
#pragma unroll
    for (int off = 128; off > 0; off >>= 1) {
        if (t < off) s[t] += s[t + off];
        __syncthreads();
    }
    if (t == 0) {
        bsum[b] = s[0];
        __threadfence();                 // publish bsum before arrival
        atomicAdd(done, 1);
    }
    if (t == 0) {
        while (atomicAdd(done, 0) < NB) { __builtin_amdgcn_s_sleep(8); }
    }
    __syncthreads();
    __threadfence();                     // acquire: see all blocks' bsum

    // phase C-1: scan the 196 block sums
    int bv = (t < NB) ? bsum[t] : 0;
    s[t] = bv;
    __syncthreads();
    for (int off = 1; off < 256; off <<= 1) {
        int u = (t >= off) ? s[t - off] : 0;
        __syncthreads();
        if (t >= off) s[t] += u;
        __syncthreads();
    }
    if (t == 0) sbase = (b == 0) ? 0 : s[b - 1];
    __syncthreads();
    // phase C-2: scan this block's 256 counts
    s[t] = v;
    __syncthreads();
    for (int off = 1; off < 256; off <<= 1) {
        int u = (t >= off) ? s[t - off] : 0;
        __syncthreads();
        if (t >= off) s[t] += u;
        __syncthreads();
    }
    if (i < NN) rowStart[i] = sbase + s[t] - v;  // global exclusive
}

// ---------------------------------------------------------------------------
// scatter_pq: [0,782) pq GEMM tiles; [782,3907) edge scatter+dist;
//             [3907,4707) zero agg (replaces serialized memset)
// rowCur (== rowStart) doubles as the allocation cursor: atomicAdd returns pos.
// eS entry packed to int2: x = (row<<16)|col (both < 2^16), y = dist bits
// ---------------------------------------------------------------------------
__global__ __launch_bounds__(256, 3) void scatter_pq_kernel(
    const ushort* __restrict__ hb, const ushort* __restrict__ We1s,
    const float* __restrict__ fb, ushort* __restrict__ Pp, ushort* __restrict__ Qq,
    const int* __restrict__ erow, const int* __restrict__ ecol,
    const float* __restrict__ xzf, int* __restrict__ rowCur,
    int2* __restrict__ eS, uint4* __restrict__ aggz) {
    __shared__ __align__(16) ushort sA[8192];   // used by pq part only
    const int tid = threadIdx.x;

    if (blockIdx.x >= 3907) {
        // ---- zero agg: 1.6e6 uint4s, grid-stride over 800 blocks
        const uint4 z = make_uint4(0, 0, 0, 0);
        int g0 = (blockIdx.x - 3907) * 256 + tid;
        const int total = NN * 128 * 4 / 16;    // 1,600,000
        for (int i = g0; i < total; i += 800 * 256) aggz[i] = z;
        return;
    }
    if (blockIdx.x >= 782) {
        int e = (blockIdx.x - 782) * 256 + tid;
        if (e >= EE) return;
        int r = erow[e], c = ecol[e];
        int pos = atomicAdd(&rowCur[r], 1);     // rowStart consumed as cursor
        float4 a = *(const float4*)(xzf + 3 * r);   // xzf padded by 4 floats
        float4 b = *(const float4*)(xzf + 3 * c);
        float dx = a.x - b.x, dy = a.y - b.y, dz = a.z - b.z;
        float u = (dx * dx + dy * dy + dz * dz) * __builtin_amdgcn_rcpf(2.0f * a.z * b.z);
        u = fminf(fmaxf(u, 0.0f), 1.0e6f);
        float d = __logf(1.0f + u + sqrtf(u * (u + 2.0f)));
        eS[pos] = make_int2((r << 16) | c, __float_as_int(d));
        return;
    }

    const int lane = tid & 63, w = tid >> 6;
    const int col = lane & 15, quad = lane >> 4;
    const int nt0 = w * 2;
    const int nA = w * 32 + col, nB = nA + 16;
    const float be1A = fb[nA], be1B = fb[nB];
    const int tile = blockIdx.x;
    const int n0 = tile * 64;
#pragma unroll
    for (int i = 0; i < 4; ++i) {
        int node = n0 + lane;
        uint4 v = (node < NN) ? *(const uint4*)(hb + (size_t)node * 128 + (w + 4 * i) * 8)
                              : make_uint4(0, 0, 0, 0);
        *(uint4*)(sA + (((lane >> 4) * 4 + i) * 64 + w * 16 + (lane & 15)) * 8) = v;
    }
    __syncthreads();

    f32x4 accP[4][2] = {}, accQ[4][2] = {};
#pragma unroll
    for (int kc = 0; kc < 4; ++kc) {
        bf16x8 bp0 = *(const bf16x8*)(We1s + ((kc * 8 + nt0)           * 64 + lane) * 8);
        bf16x8 bp1 = *(const bf16x8*)(We1s + ((kc * 8 + nt0 + 1)       * 64 + lane) * 8);
        bf16x8 bq0 = *(const bf16x8*)(We1s + (((kc + 4) * 8 + nt0)     * 64 + lane) * 8);
        bf16x8 bq1 = *(const bf16x8*)(We1s + (((kc + 4) * 8 + nt0 + 1) * 64 + lane) * 8);
#pragma unroll
        for (int g = 0; g < 4; ++g) {
            bf16x8 a = *(const bf16x8*)(sA + ((g * 4 + kc) * 64 + lane) * 8);
            accP[g][0] = __builtin_amdgcn_mfma_f32_16x16x32_bf16(a, bp0, accP[g][0], 0, 0, 0);
            accP[g][1] = __builtin_amdgcn_mfma_f32_16x16x32_bf16(a, bp1, accP[g][1], 0, 0, 0);
            accQ[g][0] = __builtin_amdgcn_mfma_f32_16x16x32_bf16(a, bq0, accQ[g][0], 0, 0, 0);
            accQ[g][1] = __builtin_amdgcn_mfma_f32_16x16x32_bf16(a, bq1, accQ[g][1], 0, 0, 0);
        }
    }
#pragma unroll
    for (int g = 0; g < 4; ++g) {
#pragma unroll
        for (int r = 0; r < 4; ++r) {
            int node = n0 + g * 16 + quad * 4 + r;
            if (node < NN) {
                size_t o = (size_t)node * 128;
                Pp[o + nA] = f2bf(accP[g][0][r] + be1A);
                Pp[o + nB] = f2bf(accP[g][1][r] + be1B);
                Qq[o + nA] = f2bf(accQ[g][0][r]);
                Qq[o + nB] = f2bf(accQ[g][1][r]);
            }
        }
    }
}

// ---------------------------------------------------------------------------
// Edge kernel (row-sorted edges), proven R7 structure (118us):
//   4 barriers/tile, gathers consumed in-phase, descriptor-only prefetch
//   m1 = silu(P'[row]+Q[col]+d*wl) -> sM (A-frags)
//   m2 = silu(m1@We2+be2) -> sOut (f32, ALIASES sM), LDS segment-reduce by row
// LDS: union(sM 16KB, sOut 33.8KB) + sRow -> 4 blocks/CU, 64 VGPR
// ---------------------------------------------------------------------------
__global__ __launch_bounds__(256, 4) void edge_kernel(
    const ushort* __restrict__ Pp, const ushort* __restrict__ Qq,
    const int2* __restrict__ eS, const ushort* __restrict__ We2s,
    const ushort* __restrict__ wlb, const float* __restrict__ fb,
    float* __restrict__ agg) {
    __shared__ __align__(16) char smem[64 * 132 * 4];   // 33792B shared: sM | sOut
    __shared__ int sRow[64];
    ushort* sM = (ushort*)smem;                         // first 16KB
    float (*sOut)[132] = (float(*)[132])smem;

    const int tid = threadIdx.x;
    const int lane = tid & 63, w = tid >> 6;
    const int col = lane & 15, quad = lane >> 4;
    const int nt0 = w * 2;

    const int nA = w * 32 + col, nB = nA + 16;
    const float be2A = fb[128 + nA], be2B = fb[128 + nB];

    // contiguous tile chunking: consecutive tiles share sorted rows -> locality
    const int ntiles = EE / 64;
    const int per = (ntiles + gridDim.x - 1) / gridDim.x;
    const int t0 = blockIdx.x * per;
    const int t1 = (t0 + per < ntiles) ? (t0 + per) : ntiles;
    if (t0 >= t1) return;

    // loop-invariant: We2 B-frags + wl chunks (ch = w+4i)
    bf16x8 B2[8];
#pragma unroll
    for (int kc = 0; kc < 4; ++kc) {
        B2[kc * 2]     = *(const bf16x8*)(We2s + ((kc * 8 + nt0)     * 64 + lane) * 8);
        B2[kc * 2 + 1] = *(const bf16x8*)(We2s + ((kc * 8 + nt0 + 1) * 64 + lane) * 8);
    }
    bf16x8 WL[4];
#pragma unroll
    for (int i = 0; i < 4; ++i) WL[i] = *(const bf16x8*)(wlb + (w + 4 * i) * 8);

    int2 ed = eS[(size_t)t0 * 64 + lane];

    for (int tile = t0; tile < t1; ++tile) {
        const int tn = (tile + 1 < t1) ? (tile + 1) : tile;
        const int2 edn = eS[(size_t)tn * 64 + lane];   // next descriptor only

        __syncthreads();   // S1: prev tile's sOut/sRow readers done
        const int r = ((unsigned)ed.x) >> 16, c = ed.x & 0xFFFF;
        const float d = __int_as_float(ed.y);
        if (w == 0) sRow[lane] = r;
        // m1 chunks ch = w+4i for edge m=lane; loads consumed in-phase
#pragma unroll
        for (int i = 0; i < 4; ++i) {
            int ch = w + 4 * i;
            bf16x8 p = *(const bf16x8*)(Pp + (size_t)r * 128 + ch * 8);
            bf16x8 q = *(const bf16x8*)(Qq + (size_t)c * 128 + ch * 8);
            ushort out8[8];
#pragma unroll
            for (int j = 0; j < 8; ++j) {
                float x = (float)p[j] + (float)q[j] + d * (float)WL[i][j];
                out8[j] = f2bf_fast(silu(x));
            }
            *(uint4*)(sM + (((lane >> 4) * 4 + i) * 64 + w * 16 + (lane & 15)) * 8) =
                *(const uint4*)out8;
        }
        ed = edn;
        __syncthreads();   // S2: sM ready

        // ---- GEMM2: m1[64,128] @ We2 (B in regs) ----
        f32x4 acc2[4][2] = {};
#pragma unroll
        for (int kc = 0; kc < 4; ++kc) {
#pragma unroll
            for (int g = 0; g < 4; ++g) {
                bf16x8 a = *(const bf16x8*)(sM + ((g * 4 + kc) * 64 + lane) * 8);
                acc2[g][0] = __builtin_amdgcn_mfma_f32_16x16x32_bf16(a, B2[kc * 2],     acc2[g][0], 0, 0, 0);
                acc2[g][1] = __builtin_amdgcn_mfma_f32_16x16x32_bf16(a, B2[kc * 2 + 1], acc2[g][1], 0, 0, 0);
            }
        }
        __syncthreads();   // S3: all sM reads done -> safe to overwrite as sOut

        // ep2: silu(+be2) -> sOut[m][n]
#pragma unroll
        for (int g = 0; g < 4; ++g) {
#pragma unroll
            for (int r4 = 0; r4 < 4; ++r4) {
                int m = g * 16 + quad * 4 + r4;
                sOut[m][nA] = silu(acc2[g][0][r4] + be2A);
                sOut[m][nB] = silu(acc2[g][1][r4] + be2B);
            }
        }
        __syncthreads();   // S4: sOut ready

        // ---- segment reduce over sorted rows: 2 halves x 128 cols ----
        {
            const int cc = tid & 127;
            const int mb = (tid >> 7) * 32;
            float acc = 0.0f;
            int prow = sRow[mb];
            for (int k = 0; k < 32; ++k) {
                int rw = sRow[mb + k];
                if (rw != prow) {
                    unsafeAtomicAdd(&agg[(size_t)prow * 128 + cc], acc);
                    acc = 0.0f;
                    prow = rw;
                }
                acc += sOut[mb + k][cc];
            }
            unsafeAtomicAdd(&agg[(size_t)prow * 128 + cc], acc);
        }
    }
}

// ---------------------------------------------------------------------------
// Node kernel: z = [h | agg/max(cnt,1)]; out = h + silu(z@Wn1+bn1)@Wn2+bn2
// ---------------------------------------------------------------------------
__global__ __launch_bounds__(256, 3) void node_kernel(
    const ushort* __restrict__ hb, const void* __restrict__ hraw,
    const void* __restrict__ xzsrc,
    const float* __restrict__ agg, const int* __restrict__ cntI,
    const ushort* __restrict__ Wn1s, const ushort* __restrict__ Wn2s,
    const float* __restrict__ fb, void* __restrict__ outv) {
    __shared__ __align__(16) ushort sA[16384];
    __shared__ __align__(16) ushort sM[8192];
    __shared__ int scnt[4];
    const int tid = threadIdx.x;
    const int lane = tid & 63, w = tid >> 6;
    const int col = lane & 15, quad = lane >> 4;
    const int nt0 = w * 2;
    const int ntiles = (NN + 63) / 64;
    const bool isf = detect_isf((const ushort*)xzsrc, tid, scnt);
    float* outf = (float*)outv;
    ushort* outu = (ushort*)outv;

    const int nA = w * 32 + col, nB = nA + 16;
    const float bn1A = fb[256 + nA], bn1B = fb[256 + nB];
    const float bn2A = fb[384 + nA], bn2B = fb[384 + nB];

    for (int tile = blockIdx.x; tile < ntiles; tile += gridDim.x) {
        __syncthreads();
        const int n0 = tile * 64;
#pragma unroll
        for (int i = 0; i < 8; ++i) {
            int kb = w + 4 * i;
            int node = n0 + lane;
            uint4 v;
            if (node < NN) {
                if (kb < 16) {
                    v = *(const uint4*)(hb + (size_t)node * 128 + kb * 8);
                } else {
                    const float* ap = agg + (size_t)node * 128 + (kb - 16) * 8;
                    float invc = __builtin_amdgcn_rcpf(fmaxf((float)cntI[node], 1.0f));
                    float4 f0 = *(const float4*)ap;
                    float4 f1 = *(const float4*)(ap + 4);
                    v.x = (unsigned int)f2bf_fast(f0.x * invc) | ((unsigned int)f2bf_fast(f0.y * invc) << 16);
                    v.y = (unsigned int)f2bf_fast(f0.z * invc) | ((unsigned int)f2bf_fast(f0.w * invc) << 16);
                    v.z = (unsigned int)f2bf_fast(f1.x * invc) | ((unsigned int)f2bf_fast(f1.y * invc) << 16);
                    v.w = (unsigned int)f2bf_fast(f1.z * invc) | ((unsigned int)f2bf_fast(f1.w * invc) << 16);
                }
            } else {
                v = make_uint4(0, 0, 0, 0);
            }
            *(uint4*)(sA + (((quad * 8 + i) * 64) + w * 16 + col) * 8) = v;
        }
        __syncthreads();

        f32x4 acc[4][2] = {};
#pragma unroll
        for (int kc = 0; kc < 8; ++kc) {
            bf16x8 b0 = *(const bf16x8*)(Wn1s + ((kc * 8 + nt0)     * 64 + lane) * 8);
            bf16x8 b1 = *(const bf16x8*)(Wn1s + ((kc * 8 + nt0 + 1) * 64 + lane) * 8);
#pragma unroll
            for (int g = 0; g < 4; ++g) {
                bf16x8 a = *(const bf16x8*)(sA + ((g * 8 + kc) * 64 + lane) * 8);
                acc[g][0] = __builtin_amdgcn_mfma_f32_16x16x32_bf16(a, b0, acc[g][0], 0, 0, 0);
                acc[g][1] = __builtin_amdgcn_mfma_f32_16x16x32_bf16(a, b1, acc[g][1], 0, 0, 0);
            }
        }
#pragma unroll
        for (int g = 0; g < 4; ++g) {
            int base0 = ((g * 4 + w) * 64 + (col >> 3) * 16) * 8 + (col & 7);
#pragma unroll
            for (int r = 0; r < 4; ++r) {
                int mrow = quad * 4 + r;
                sM[base0 + mrow * 8]              = f2bf_fast(silu(acc[g][0][r] + bn1A));
                sM[base0 + 2 * 16 * 8 + mrow * 8] = f2bf_fast(silu(acc[g][1][r] + bn1B));
            }
        }
        __syncthreads();

        f32x4 acc2[4][2] = {};
#pragma unroll
        for (int kc = 0; kc < 4; ++kc) {
            bf16x8 b0 = *(const bf16x8*)(Wn2s + ((kc * 8 + nt0)     * 64 + lane) * 8);
            bf16x8 b1 = *(const bf16x8*)(Wn2s + ((kc * 8 + nt0 + 1) * 64 + lane) * 8);
#pragma unroll
            for (int g = 0; g < 4; ++g) {
                bf16x8 a = *(const bf16x8*)(sM + ((g * 4 + kc) * 64 + lane) * 8);
                acc2[g][0] = __builtin_amdgcn_mfma_f32_16x16x32_bf16(a, b0, acc2[g][0], 0, 0, 0);
                acc2[g][1] = __builtin_amdgcn_mfma_f32_16x16x32_bf16(a, b1, acc2[g][1], 0, 0, 0);
            }
        }
#pragma unroll
        for (int g = 0; g < 4; ++g) {
#pragma unroll
            for (int r = 0; r < 4; ++r) {
                int ml2 = g * 16 + quad * 4 + r;
                int node = n0 + ml2;
                if (node < NN) {
                    size_t oi = (size_t)node * 128;
                    float h0 = isf ? ((const float*)hraw)[oi + nA] : bf2f(((const ushort*)hraw)[oi + nA]);
                    float h1 = isf ? ((const float*)hraw)[oi + nB] : bf2f(((const ushort*)hraw)[oi + nB]);
                    float x0 = acc2[g][0][r] + bn2A + h0;
                    float x1 = acc2[g][1][r] + bn2B + h1;
                    if (isf) { outf[oi + nA] = x0; outf[oi + nB] = x1; }
                    else     { outu[oi + nA] = f2bf_fast(x0); outu[oi + nB] = f2bf_fast(x1); }
                }
            }
        }
    }
}

extern "C" void kernel_launch(void* const* d_in, const int* in_sizes, int n_in,
                              void* d_out, int out_size, void* d_ws, size_t ws_size,
                              hipStream_t stream) {
    const void* xz  = d_in[0];
    const void* h   = d_in[1];
    const void* We1 = d_in[2];
    const void* be1 = d_in[3];
    const void* We2 = d_in[4];
    const void* be2 = d_in[5];
    const void* Wn1 = d_in[6];
    const void* bn1 = d_in[7];
    const void* Wn2 = d_in[8];
    const void* bn2 = d_in[9];
    const int*  ei  = (const int*)d_in[10];
    const int* erow = ei;
    const int* ecol = ei + EE;

    char* base = (char*)d_ws;
    size_t cur = 0;
    auto alloc = [&](size_t bytes) { size_t o = cur; cur = (cur + bytes + 255) & ~(size_t)255; return o; };
    float*  agg    = (float*) (base + alloc((size_t)NN * 128 * 4));
    int*    cntI   = (int*)   (base + alloc((size_t)NN * 4));
    int*    done   = (int*)   (base + alloc(256));
    ushort* hb     = (ushort*)(base + alloc((size_t)NN * 128 * 2));
    ushort* Pp     = (ushort*)(base + alloc((size_t)NN * 128 * 2));
    ushort* Qq     = (ushort*)(base + alloc((size_t)NN * 128 * 2));
    int2*   eS     = (int2*)  (base + alloc((size_t)EE * 8));
    float*  xzf    = (float*) (base + alloc((size_t)NN * 3 * 4 + 16));   // +pad for float4 loads
    int*    rowSt  = (int*)   (base + alloc((size_t)NN * 4));
    int*    bsum   = (int*)   (base + alloc(256 * 4));
    ushort* We1s   = (ushort*)(base + alloc(32768 * 2));
    ushort* We2s   = (ushort*)(base + alloc(16384 * 2));
    ushort* Wn1s   = (ushort*)(base + alloc(32768 * 2));
    ushort* Wn2s   = (ushort*)(base + alloc(16384 * 2));
    float*  fb     = (float*) (base + alloc(640 * 4));
    ushort* wlb    = (ushort*)(base + alloc(128 * 2));

    // zero cntI + done (adjacent) before prep's atomics / scan's arrival ctr;
    // agg is zeroed inside scatter_pq (overlapped), first consumed by edge_kernel.
    size_t zbytes = (size_t)((char*)hb - (char*)cntI);
    (void)hipMemsetAsync(cntI, 0, zbytes, stream);

    prep_all_kernel<<<6886, 256, 0, stream>>>(h, xz, erow, We1, We2, Wn1, Wn2,
                                              be1, be2, bn1, bn2,
                                              hb, xzf, cntI, We1s, We2s, Wn1s, Wn2s,
                                              fb, wlb);
    scan_fused_kernel<<<NB, 256, 0, stream>>>(cntI, bsum, rowSt, done);
    scatter_pq_kernel<<<782 + 3125 + 800, 256, 0, stream>>>(hb, We1s, fb, Pp, Qq,
                                                            erow, ecol, xzf, rowSt,
                                                            eS, (uint4*)agg);
    edge_kernel<<<1024, 256, 0, stream>>>(Pp, Qq, eS, We2s, wlb, fb, agg);
    node_kernel<<<782, 256, 0, stream>>>(hb, h, xz, agg, cntI, Wn1s, Wn2s, fb, d_out);
}

// Round 10
// 325.797 us; speedup vs baseline: 1.3175x; 1.0653x over previous
//
#include <hip/hip_runtime.h>

#define NN 50000
#define EE 800000
#define NB 196   // ceil(NN/256)

typedef __bf16 bf16x8 __attribute__((ext_vector_type(8)));
typedef float  f32x4  __attribute__((ext_vector_type(4)));

__device__ __forceinline__ float bf2f(ushort u) {
    union { unsigned int i; float f; } v; v.i = ((unsigned int)u) << 16; return v.f;
}
__device__ __forceinline__ ushort f2bf(float f) {        // RNE
    union { float f; unsigned int i; } v; v.f = f;
    unsigned int u = v.i;
    return (ushort)((u + 0x7FFFu + ((u >> 16) & 1u)) >> 16);
}
__device__ __forceinline__ ushort f2bf_fast(float f) {
    union { float f; unsigned int i; } v; v.f = f;
    return (ushort)((v.i + 0x8000u) >> 16);
}
// fast silu: v_rcp_f32 instead of IEEE division (error ~1ulp f32 << bf16 rounding)
__device__ __forceinline__ float silu(float x) {
    return x * __builtin_amdgcn_rcpf(1.0f + __expf(-x));
}

// Inline dtype detection: every 256-thread block samples the first 256
// bf16-candidates of xz; if they look sane (finite, |v|<=4) input is bf16.
__device__ __forceinline__ bool detect_isf(const ushort* __restrict__ xzu,
                                           int tid, int* scnt) {
    float v = bf2f(xzu[2 * (tid & 255)]);
    bool sane = (v == v) && (fabsf(v) <= 4.0f);
    unsigned long long m = __ballot(sane);
    if ((tid & 63) == 0) scnt[tid >> 6] = __popcll(m);
    __syncthreads();
    int cnt = scnt[0] + scnt[1] + scnt[2] + scnt[3];
    return cnt < 192;   // true -> f32 input
}

// ---------------------------------------------------------------------------
// prep_all: [0,3125) h->bf16; [3125,3712) xz->f32; [3712,6837) degree;
//           [6837,6886) weight swizzle + misc
// ---------------------------------------------------------------------------
__global__ void prep_all_kernel(const void* __restrict__ hsrc, const void* __restrict__ xzsrc,
                                const int* __restrict__ erow,
                                const void* We1, const void* We2,
                                const void* Wn1, const void* Wn2,
                                const void* be1, const void* be2,
                                const void* bn1, const void* bn2,
                                ushort* __restrict__ hb, float* __restrict__ xzf,
                                int* __restrict__ cntI,
                                ushort* __restrict__ We1s, ushort* __restrict__ We2s,
                                ushort* __restrict__ Wn1s, ushort* __restrict__ Wn2s,
                                float* __restrict__ fb, ushort* __restrict__ wlb) {
    __shared__ int scnt[4];
    const int b = blockIdx.x;
    const int tid = threadIdx.x;

    if (b >= 3712 && b < 6837) {          // degree count: no dtype needed
        int e = (b - 3712) * 256 + tid;
        if (e < EE) atomicAdd(&cntI[erow[e]], 1);
        return;
    }

    const bool isf = detect_isf((const ushort*)xzsrc, tid, scnt);

    if (b < 3125) {                        // h -> bf16 (8 elems/thread)
        int i = (b * 256 + tid) * 8;
        uint4 o;
        if (isf) {
            const float* s = (const float*)hsrc + i;
            float4 f0 = *(const float4*)s;
            float4 f1 = *(const float4*)(s + 4);
            o.x = (unsigned int)f2bf(f0.x) | ((unsigned int)f2bf(f0.y) << 16);
            o.y = (unsigned int)f2bf(f0.z) | ((unsigned int)f2bf(f0.w) << 16);
            o.z = (unsigned int)f2bf(f1.x) | ((unsigned int)f2bf(f1.y) << 16);
            o.w = (unsigned int)f2bf(f1.z) | ((unsigned int)f2bf(f1.w) << 16);
        } else {
            o = *(const uint4*)((const ushort*)hsrc + i);
        }
        *(uint4*)(hb + i) = o;
    } else if (b < 3712) {                 // xz -> f32
        int i = (b - 3125) * 256 + tid;
        if (i < NN * 3)
            xzf[i] = isf ? ((const float*)xzsrc)[i] : bf2f(((const ushort*)xzsrc)[i]);
    } else {                               // weight swizzle / misc
        int sw = b - 6837;
        if (sw == 48) {
            for (int j = tid; j < 640; j += 256) {
                int which = j >> 7, k = j & 127;
                const void* src = (which == 0) ? be1 : (which == 1) ? be2 :
                                  (which == 2) ? bn1 : (which == 3) ? bn2 : We1;
                size_t idx = (which == 4) ? ((size_t)256 * 128 + k) : (size_t)k;
                float v = isf ? ((const float*)src)[idx] : bf2f(((const ushort*)src)[idx]);
                fb[j] = v;
                if (which == 4) wlb[k] = f2bf(v);
            }
            return;
        }
        int c = sw * 256 + tid;
        const void* src; ushort* dst; int cl;
        if      (c <  4096) { src = We1; dst = We1s; cl = c;         }
        else if (c <  6144) { src = We2; dst = We2s; cl = c - 4096;  }
        else if (c < 10240) { src = Wn1; dst = Wn1s; cl = c - 6144;  }
        else                { src = Wn2; dst = Wn2s; cl = c - 10240; }
        int l = cl & 63, nt = (cl >> 6) & 7, kc = cl >> 9;
        int kbase = kc * 32 + (l >> 4) * 8;
        int n = nt * 16 + (l & 15);
        ushort tmp[8];
#pragma unroll
        for (int j = 0; j < 8; ++j) {
            size_t idx = (size_t)(kbase + j) * 128 + n;
            tmp[j] = isf ? f2bf(((const float*)src)[idx]) : ((const ushort*)src)[idx];
        }
#pragma unroll
        for (int j = 0; j < 8; ++j) dst[(size_t)cl * 8 + j] = tmp[j];
    }
}

// ---------------------------------------------------------------------------
// Counting-sort scan: A) per-block sums  C) scan bsum in-block + write rowStart
// (separate kernels — R9's fused spin-wait version regressed)
// ---------------------------------------------------------------------------
__global__ void scanA_kernel(const int* __restrict__ cntI, int* __restrict__ bsum) {
    __shared__ int s[256];
    int t = threadIdx.x;
    int i = blockIdx.x * 256 + t;
    s[t] = (i < NN) ? cntI[i] : 0;
    __syncthreads();
#pragma unroll
    for (int off = 128; off > 0; off >>= 1) {
        if (t < off) s[t] += s[t + off];
        __syncthreads();
    }
    if (t == 0) bsum[blockIdx.x] = s[0];
}

__global__ void scanC_kernel(const int* __restrict__ cntI, const int* __restrict__ bsum,
                             int* __restrict__ rowStart) {
    __shared__ int s[256];
    __shared__ int sbase;
    int t = threadIdx.x;
    int bv = (t < NB) ? bsum[t] : 0;
    s[t] = bv;
    __syncthreads();
    for (int off = 1; off < 256; off <<= 1) {
        int u = (t >= off) ? s[t - off] : 0;
        __syncthreads();
        if (t >= off) s[t] += u;
        __syncthreads();
    }
    if (t == 0) sbase = (blockIdx.x == 0) ? 0 : s[blockIdx.x - 1];
    __syncthreads();
    int i = blockIdx.x * 256 + t;
    int v = (i < NN) ? cntI[i] : 0;
    s[t] = v;
    __syncthreads();
    for (int off = 1; off < 256; off <<= 1) {
        int u = (t >= off) ? s[t - off] : 0;
        __syncthreads();
        if (t >= off) s[t] += u;
        __syncthreads();
    }
    if (i < NN) rowStart[i] = sbase + s[t] - v;  // global exclusive
}

// ---------------------------------------------------------------------------
// scatter_pq: [0,782) pq GEMM tiles; [782,3907) edge scatter+dist;
//             [3907,4707) zero agg (replaces serialized memset)
// rowCur (== rowStart) doubles as the allocation cursor: atomicAdd returns pos.
// eS entry packed to int2: x = (row<<16)|col (both < 2^16), y = dist bits
// ---------------------------------------------------------------------------
__global__ __launch_bounds__(256, 3) void scatter_pq_kernel(
    const ushort* __restrict__ hb, const ushort* __restrict__ We1s,
    const float* __restrict__ fb, ushort* __restrict__ Pp, ushort* __restrict__ Qq,
    const int* __restrict__ erow, const int* __restrict__ ecol,
    const float* __restrict__ xzf, int* __restrict__ rowCur,
    int2* __restrict__ eS, uint4* __restrict__ aggz) {
    __shared__ __align__(16) ushort sA[8192];   // used by pq part only
    const int tid = threadIdx.x;

    if (blockIdx.x >= 3907) {
        // ---- zero agg: 1.6e6 uint4s, grid-stride over 800 blocks
        const uint4 z = make_uint4(0, 0, 0, 0);
        int g0 = (blockIdx.x - 3907) * 256 + tid;
        const int total = NN * 128 * 4 / 16;    // 1,600,000
        for (int i = g0; i < total; i += 800 * 256) aggz[i] = z;
        return;
    }
    if (blockIdx.x >= 782) {
        int e = (blockIdx.x - 782) * 256 + tid;
        if (e >= EE) return;
        int r = erow[e], c = ecol[e];
        int pos = atomicAdd(&rowCur[r], 1);     // rowStart consumed as cursor
        float4 a = *(const float4*)(xzf + 3 * r);   // xzf padded by 4 floats
        float4 b = *(const float4*)(xzf + 3 * c);
        float dx = a.x - b.x, dy = a.y - b.y, dz = a.z - b.z;
        float u = (dx * dx + dy * dy + dz * dz) * __builtin_amdgcn_rcpf(2.0f * a.z * b.z);
        u = fminf(fmaxf(u, 0.0f), 1.0e6f);
        float d = __logf(1.0f + u + sqrtf(u * (u + 2.0f)));
        eS[pos] = make_int2((r << 16) | c, __float_as_int(d));
        return;
    }

    const int lane = tid & 63, w = tid >> 6;
    const int col = lane & 15, quad = lane >> 4;
    const int nt0 = w * 2;
    const int nA = w * 32 + col, nB = nA + 16;
    const float be1A = fb[nA], be1B = fb[nB];
    const int tile = blockIdx.x;
    const int n0 = tile * 64;
#pragma unroll
    for (int i = 0; i < 4; ++i) {
        int node = n0 + lane;
        uint4 v = (node < NN) ? *(const uint4*)(hb + (size_t)node * 128 + (w + 4 * i) * 8)
                              : make_uint4(0, 0, 0, 0);
        *(uint4*)(sA + (((lane >> 4) * 4 + i) * 64 + w * 16 + (lane & 15)) * 8) = v;
    }
    __syncthreads();

    f32x4 accP[4][2] = {}, accQ[4][2] = {};
#pragma unroll
    for (int kc = 0; kc < 4; ++kc) {
        bf16x8 bp0 = *(const bf16x8*)(We1s + ((kc * 8 + nt0)           * 64 + lane) * 8);
        bf16x8 bp1 = *(const bf16x8*)(We1s + ((kc * 8 + nt0 + 1)       * 64 + lane) * 8);
        bf16x8 bq0 = *(const bf16x8*)(We1s + (((kc + 4) * 8 + nt0)     * 64 + lane) * 8);
        bf16x8 bq1 = *(const bf16x8*)(We1s + (((kc + 4) * 8 + nt0 + 1) * 64 + lane) * 8);
#pragma unroll
        for (int g = 0; g < 4; ++g) {
            bf16x8 a = *(const bf16x8*)(sA + ((g * 4 + kc) * 64 + lane) * 8);
            accP[g][0] = __builtin_amdgcn_mfma_f32_16x16x32_bf16(a, bp0, accP[g][0], 0, 0, 0);
            accP[g][1] = __builtin_amdgcn_mfma_f32_16x16x32_bf16(a, bp1, accP[g][1], 0, 0, 0);
            accQ[g][0] = __builtin_amdgcn_mfma_f32_16x16x32_bf16(a, bq0, accQ[g][0], 0, 0, 0);
            accQ[g][1] = __builtin_amdgcn_mfma_f32_16x16x32_bf16(a, bq1, accQ[g][1], 0, 0, 0);
        }
    }
#pragma unroll
    for (int g = 0; g < 4; ++g) {
#pragma unroll
        for (int r = 0; r < 4; ++r) {
            int node = n0 + g * 16 + quad * 4 + r;
            if (node < NN) {
                size_t o = (size_t)node * 128;
                Pp[o + nA] = f2bf(accP[g][0][r] + be1A);
                Pp[o + nB] = f2bf(accP[g][1][r] + be1B);
                Qq[o + nA] = f2bf(accQ[g][0][r]);
                Qq[o + nB] = f2bf(accQ[g][1][r]);
            }
        }
    }
}

// ---------------------------------------------------------------------------
// Edge kernel: R7 dataflow + two-pass 32-row sOut for occupancy.
// LDS = union(sM 16KB, sOut 32x132 f32 16.9KB) + sRow = 17.4KB -> 8 blocks/CU.
// launch_bounds(256,4) (NOT 6 — R8's min-waves=6 forced VGPR 40 and spilled
// the accumulators; at lb4 the proven 64-VGPR allocation is preserved).
// per tile: S1 | m1->sM | S2 | GEMM2 | S3 | epA | S4 | redA | S5 | epB | S6 | redB
// ---------------------------------------------------------------------------
__global__ __launch_bounds__(256, 4) void edge_kernel(
    const ushort* __restrict__ Pp, const ushort* __restrict__ Qq,
    const int2* __restrict__ eS, const ushort* __restrict__ We2s,
    const ushort* __restrict__ wlb, const float* __restrict__ fb,
    float* __restrict__ agg) {
    __shared__ __align__(16) char smem[32 * 132 * 4];   // 16896B: sM(16384) | sOut32
    __shared__ int sRow[64];
    ushort* sM = (ushort*)smem;                         // first 16KB
    float (*sOut)[132] = (float(*)[132])smem;           // 32 rows x 132 f32

    const int tid = threadIdx.x;
    const int lane = tid & 63, w = tid >> 6;
    const int col = lane & 15, quad = lane >> 4;
    const int nt0 = w * 2;

    const int nA = w * 32 + col, nB = nA + 16;
    const float be2A = fb[128 + nA], be2B = fb[128 + nB];

    // contiguous tile chunking: consecutive tiles share sorted rows -> locality
    const int ntiles = EE / 64;
    const int per = (ntiles + gridDim.x - 1) / gridDim.x;
    const int t0 = blockIdx.x * per;
    const int t1 = (t0 + per < ntiles) ? (t0 + per) : ntiles;
    if (t0 >= t1) return;

    // loop-invariant: We2 B-frags + wl chunks (ch = w+4i) — resident as in R7
    bf16x8 B2[8];
#pragma unroll
    for (int kc = 0; kc < 4; ++kc) {
        B2[kc * 2]     = *(const bf16x8*)(We2s + ((kc * 8 + nt0)     * 64 + lane) * 8);
        B2[kc * 2 + 1] = *(const bf16x8*)(We2s + ((kc * 8 + nt0 + 1) * 64 + lane) * 8);
    }
    bf16x8 WL[4];
#pragma unroll
    for (int i = 0; i < 4; ++i) WL[i] = *(const bf16x8*)(wlb + (w + 4 * i) * 8);

    int2 ed = eS[(size_t)t0 * 64 + lane];

    for (int tile = t0; tile < t1; ++tile) {
        const int tn = (tile + 1 < t1) ? (tile + 1) : tile;
        const int2 edn = eS[(size_t)tn * 64 + lane];   // next descriptor only

        __syncthreads();   // S1: prev tile's redB readers done (sOut/sRow free)
        const int r = ((unsigned)ed.x) >> 16, c = ed.x & 0xFFFF;
        const float d = __int_as_float(ed.y);
        if (w == 0) sRow[lane] = r;
        // m1 chunks ch = w+4i for edge m=lane; loads consumed in-phase
#pragma unroll
        for (int i = 0; i < 4; ++i) {
            int ch = w + 4 * i;
            bf16x8 p = *(const bf16x8*)(Pp + (size_t)r * 128 + ch * 8);
            bf16x8 q = *(const bf16x8*)(Qq + (size_t)c * 128 + ch * 8);
            ushort out8[8];
#pragma unroll
            for (int j = 0; j < 8; ++j) {
                float x = (float)p[j] + (float)q[j] + d * (float)WL[i][j];
                out8[j] = f2bf_fast(silu(x));
            }
            *(uint4*)(sM + (((lane >> 4) * 4 + i) * 64 + w * 16 + (lane & 15)) * 8) =
                *(const uint4*)out8;
        }
        ed = edn;
        __syncthreads();   // S2: sM ready

        // ---- GEMM2: m1[64,128] @ We2 (B in regs) ----
        f32x4 acc2[4][2] = {};
#pragma unroll
        for (int kc = 0; kc < 4; ++kc) {
#pragma unroll
            for (int g = 0; g < 4; ++g) {
                bf16x8 a = *(const bf16x8*)(sM + ((g * 4 + kc) * 64 + lane) * 8);
                acc2[g][0] = __builtin_amdgcn_mfma_f32_16x16x32_bf16(a, B2[kc * 2],     acc2[g][0], 0, 0, 0);
                acc2[g][1] = __builtin_amdgcn_mfma_f32_16x16x32_bf16(a, B2[kc * 2 + 1], acc2[g][1], 0, 0, 0);
            }
        }
        __syncthreads();   // S3: all sM reads done -> safe to overwrite as sOut

        // ---- two passes: ep2 (32 rows) + segment reduce (16 rows/thread) ----
#pragma unroll
        for (int pass = 0; pass < 2; ++pass) {
#pragma unroll
            for (int gg = 0; gg < 2; ++gg) {
                int g = pass * 2 + gg;
#pragma unroll
                for (int r4 = 0; r4 < 4; ++r4) {
                    int lr = gg * 16 + quad * 4 + r4;   // local row 0..31
                    sOut[lr][nA] = silu(acc2[g][0][r4] + be2A);
                    sOut[lr][nB] = silu(acc2[g][1][r4] + be2B);
                }
            }
            __syncthreads();   // S4/S6: sOut pass ready

            {
                const int cc = tid & 127;
                const int sub = tid >> 7;                 // 0,1
                const int mb = pass * 32 + sub * 16;      // global row base
                float acc = 0.0f;
                int prow = sRow[mb];
                for (int k = 0; k < 16; ++k) {
                    int rw = sRow[mb + k];
                    if (rw != prow) {
                        unsafeAtomicAdd(&agg[(size_t)prow * 128 + cc], acc);
                        acc = 0.0f;
                        prow = rw;
                    }
                    acc += sOut[sub * 16 + k][cc];
                }
                unsafeAtomicAdd(&agg[(size_t)prow * 128 + cc], acc);
            }
            if (pass == 0) __syncthreads();   // S5: redA done before epB overwrites
        }
    }
}

// ---------------------------------------------------------------------------
// Node kernel: z = [h | agg/max(cnt,1)]; out = h + silu(z@Wn1+bn1)@Wn2+bn2
// ---------------------------------------------------------------------------
__global__ __launch_bounds__(256, 3) void node_kernel(
    const ushort* __restrict__ hb, const void* __restrict__ hraw,
    const void* __restrict__ xzsrc,
    const float* __restrict__ agg, const int* __restrict__ cntI,
    const ushort* __restrict__ Wn1s, const ushort* __restrict__ Wn2s,
    const float* __restrict__ fb, void* __restrict__ outv) {
    __shared__ __align__(16) ushort sA[16384];
    __shared__ __align__(16) ushort sM[8192];
    __shared__ int scnt[4];
    const int tid = threadIdx.x;
    const int lane = tid & 63, w = tid >> 6;
    const int col = lane & 15, quad = lane >> 4;
    const int nt0 = w * 2;
    const int ntiles = (NN + 63) / 64;
    const bool isf = detect_isf((const ushort*)xzsrc, tid, scnt);
    float* outf = (float*)outv;
    ushort* outu = (ushort*)outv;

    const int nA = w * 32 + col, nB = nA + 16;
    const float bn1A = fb[256 + nA], bn1B = fb[256 + nB];
    const float bn2A = fb[384 + nA], bn2B = fb[384 + nB];

    for (int tile = blockIdx.x; tile < ntiles; tile += gridDim.x) {
        __syncthreads();
        const int n0 = tile * 64;
#pragma unroll
        for (int i = 0; i < 8; ++i) {
            int kb = w + 4 * i;
            int node = n0 + lane;
            uint4 v;
            if (node < NN) {
                if (kb < 16) {
                    v = *(const uint4*)(hb + (size_t)node * 128 + kb * 8);
                } else {
                    const float* ap = agg + (size_t)node * 128 + (kb - 16) * 8;
                    float invc = __builtin_amdgcn_rcpf(fmaxf((float)cntI[node], 1.0f));
                    float4 f0 = *(const float4*)ap;
                    float4 f1 = *(const float4*)(ap + 4);
                    v.x = (unsigned int)f2bf_fast(f0.x * invc) | ((unsigned int)f2bf_fast(f0.y * invc) << 16);
                    v.y = (unsigned int)f2bf_fast(f0.z * invc) | ((unsigned int)f2bf_fast(f0.w * invc) << 16);
                    v.z = (unsigned int)f2bf_fast(f1.x * invc) | ((unsigned int)f2bf_fast(f1.y * invc) << 16);
                    v.w = (unsigned int)f2bf_fast(f1.z * invc) | ((unsigned int)f2bf_fast(f1.w * invc) << 16);
                }
            } else {
                v = make_uint4(0, 0, 0, 0);
            }
            *(uint4*)(sA + (((quad * 8 + i) * 64) + w * 16 + col) * 8) = v;
        }
        __syncthreads();

        f32x4 acc[4][2] = {};
#pragma unroll
        for (int kc = 0; kc < 8; ++kc) {
            bf16x8 b0 = *(const bf16x8*)(Wn1s + ((kc * 8 + nt0)     * 64 + lane) * 8);
            bf16x8 b1 = *(const bf16x8*)(Wn1s + ((kc * 8 + nt0 + 1) * 64 + lane) * 8);
#pragma unroll
            for (int g = 0; g < 4; ++g) {
                bf16x8 a = *(const bf16x8*)(sA + ((g * 8 + kc) * 64 + lane) * 8);
                acc[g][0] = __builtin_amdgcn_mfma_f32_16x16x32_bf16(a, b0, acc[g][0], 0, 0, 0);
                acc[g][1] = __builtin_amdgcn_mfma_f32_16x16x32_bf16(a, b1, acc[g][1], 0, 0, 0);
            }
        }
#pragma unroll
        for (int g = 0; g < 4; ++g) {
            int base0 = ((g * 4 + w) * 64 + (col >> 3) * 16) * 8 + (col & 7);
#pragma unroll
            for (int r = 0; r < 4; ++r) {
                int mrow = quad * 4 + r;
                sM[base0 + mrow * 8]              = f2bf_fast(silu(acc[g][0][r] + bn1A));
                sM[base0 + 2 * 16 * 8 + mrow * 8] = f2bf_fast(silu(acc[g][1][r] + bn1B));
            }
        }
        __syncthreads();

        f32x4 acc2[4][2] = {};
#pragma unroll
        for (int kc = 0; kc < 4; ++kc) {
            bf16x8 b0 = *(const bf16x8*)(Wn2s + ((kc * 8 + nt0)     * 64 + lane) * 8);
            bf16x8 b1 = *(const bf16x8*)(Wn2s + ((kc * 8 + nt0 + 1) * 64 + lane) * 8);
#pragma unroll
            for (int g = 0; g < 4; ++g) {
                bf16x8 a = *(const bf16x8*)(sM + ((g * 4 + kc) * 64 + lane) * 8);
                acc2[g][0] = __builtin_amdgcn_mfma_f32_16x16x32_bf16(a, b0, acc2[g][0], 0, 0, 0);
                acc2[g][1] = __builtin_amdgcn_mfma_f32_16x16x32_bf16(a, b1, acc2[g][1], 0, 0, 0);
            }
        }
#pragma unroll
        for (int g = 0; g < 4; ++g) {
#pragma unroll
            for (int r = 0; r < 4; ++r) {
                int ml2 = g * 16 + quad * 4 + r;
                int node = n0 + ml2;
                if (node < NN) {
                    size_t oi = (size_t)node * 128;
                    float h0 = isf ? ((const float*)hraw)[oi + nA] : bf2f(((const ushort*)hraw)[oi + nA]);
                    float h1 = isf ? ((const float*)hraw)[oi + nB] : bf2f(((const ushort*)hraw)[oi + nB]);
                    float x0 = acc2[g][0][r] + bn2A + h0;
                    float x1 = acc2[g][1][r] + bn2B + h1;
                    if (isf) { outf[oi + nA] = x0; outf[oi + nB] = x1; }
                    else     { outu[oi + nA] = f2bf_fast(x0); outu[oi + nB] = f2bf_fast(x1); }
                }
            }
        }
    }
}

extern "C" void kernel_launch(void* const* d_in, const int* in_sizes, int n_in,
                              void* d_out, int out_size, void* d_ws, size_t ws_size,
                              hipStream_t stream) {
    const void* xz  = d_in[0];
    const void* h   = d_in[1];
    const void* We1 = d_in[2];
    const void* be1 = d_in[3];
    const void* We2 = d_in[4];
    const void* be2 = d_in[5];
    const void* Wn1 = d_in[6];
    const void* bn1 = d_in[7];
    const void* Wn2 = d_in[8];
    const void* bn2 = d_in[9];
    const int*  ei  = (const int*)d_in[10];
    const int* erow = ei;
    const int* ecol = ei + EE;

    char* base = (char*)d_ws;
    size_t cur = 0;
    auto alloc = [&](size_t bytes) { size_t o = cur; cur = (cur + bytes + 255) & ~(size_t)255; return o; };
    float*  agg    = (float*) (base + alloc((size_t)NN * 128 * 4));
    int*    cntI   = (int*)   (base + alloc((size_t)NN * 4));
    ushort* hb     = (ushort*)(base + alloc((size_t)NN * 128 * 2));
    ushort* Pp     = (ushort*)(base + alloc((size_t)NN * 128 * 2));
    ushort* Qq     = (ushort*)(base + alloc((size_t)NN * 128 * 2));
    int2*   eS     = (int2*)  (base + alloc((size_t)EE * 8));
    float*  xzf    = (float*) (base + alloc((size_t)NN * 3 * 4 + 16));   // +pad for float4 loads
    int*    rowSt  = (int*)   (base + alloc((size_t)NN * 4));
    int*    bsum   = (int*)   (base + alloc(256 * 4));
    ushort* We1s   = (ushort*)(base + alloc(32768 * 2));
    ushort* We2s   = (ushort*)(base + alloc(16384 * 2));
    ushort* Wn1s   = (ushort*)(base + alloc(32768 * 2));
    ushort* Wn2s   = (ushort*)(base + alloc(16384 * 2));
    float*  fb     = (float*) (base + alloc(640 * 4));
    ushort* wlb    = (ushort*)(base + alloc(128 * 2));

    // zero cntI before prep's atomics; agg is zeroed inside scatter_pq
    // (overlapped), first consumed by edge_kernel afterwards.
    size_t zbytes = (size_t)((char*)hb - (char*)cntI);
    (void)hipMemsetAsync(cntI, 0, zbytes, stream);

    prep_all_kernel<<<6886, 256, 0, stream>>>(h, xz, erow, We1, We2, Wn1, Wn2,
                                              be1, be2, bn1, bn2,
                                              hb, xzf, cntI, We1s, We2s, Wn1s, Wn2s,
                                              fb, wlb);
    scanA_kernel<<<NB, 256, 0, stream>>>(cntI, bsum);
    scanC_kernel<<<NB, 256, 0, stream>>>(cntI, bsum, rowSt);
    scatter_pq_kernel<<<782 + 3125 + 800, 256, 0, stream>>>(hb, We1s, fb, Pp, Qq,
                                                            erow, ecol, xzf, rowSt,
                                                            eS, (uint4*)agg);
    edge_kernel<<<2048, 256, 0, stream>>>(Pp, Qq, eS, We2s, wlb, fb, agg);
    node_kernel<<<782, 256, 0, stream>>>(hb, h, xz, agg, cntI, Wn1s, Wn2s, fb, d_out);
}